// Round 1
// baseline (920.496 us; speedup 1.0000x reference)
//
#include <hip/hip_runtime.h>
#include <hip/hip_bf16.h>

#define N_ATOMS_C 50000
#define N_PAIRS_C 800000
#define C_DIM 64

// One wave (64 lanes) per pair. lane = channel.
// ix[p,x,c] = (p3[j,x,c] + d3[p,x]) * i1[p,c]; atomicAdd into agg[i,x,c].
__global__ __launch_bounds__(256) void scatter_kernel(
    const int* __restrict__ ind, const float* __restrict__ p3,
    const float* __restrict__ i1, const float* __restrict__ d3,
    float* __restrict__ agg, int n_pairs) {
  int pair = blockIdx.x * 4 + (threadIdx.x >> 6);
  if (pair >= n_pairs) return;
  int lane = threadIdx.x & 63;

  int i = ind[pair * 2 + 0];
  int j = ind[pair * 2 + 1];
  float gate = i1[pair * (size_t)C_DIM + lane];
  float d0 = d3[pair * 3 + 0];
  float d1 = d3[pair * 3 + 1];
  float d2 = d3[pair * 3 + 2];

  const float* pj = p3 + (size_t)j * (3 * C_DIM);
  float v0 = (pj[lane] + d0) * gate;
  float v1 = (pj[C_DIM + lane] + d1) * gate;
  float v2 = (pj[2 * C_DIM + lane] + d2) * gate;

  float* ai = agg + (size_t)i * (3 * C_DIM);
  atomicAdd(ai + lane, v0);
  atomicAdd(ai + C_DIM + lane, v1);
  atomicAdd(ai + 2 * C_DIM + lane, v2);
}

// One wave per atom. lane = output channel d.
// p3_new[a,x,d] = sum_c agg[a,x,c] * W[d,c]
// dotted[a,d]   = sum_x p3_new[a,x,d]^2
__global__ __launch_bounds__(256) void gemm_kernel(
    const float* __restrict__ agg, const float* __restrict__ W,
    float* __restrict__ p3_new, float* __restrict__ dotted, int n_atoms) {
  // Wt[c][d] = W[d][c]; lane d reads Wt[c*64+d] -> consecutive, conflict-free.
  __shared__ float Wt[C_DIM * C_DIM];
  for (int idx = threadIdx.x; idx < C_DIM * C_DIM; idx += 256) {
    int d = idx >> 6, c = idx & 63;
    Wt[c * C_DIM + d] = W[idx];
  }
  __syncthreads();

  int atom = blockIdx.x * 4 + (threadIdx.x >> 6);
  if (atom >= n_atoms) return;
  int lane = threadIdx.x & 63;

  const float* a = agg + (size_t)atom * (3 * C_DIM);
  float r0 = a[lane];
  float r1 = a[C_DIM + lane];
  float r2 = a[2 * C_DIM + lane];

  float o0 = 0.f, o1 = 0.f, o2 = 0.f;
#pragma unroll
  for (int c = 0; c < C_DIM; ++c) {
    float w = Wt[c * C_DIM + lane];
    o0 += __shfl(r0, c) * w;
    o1 += __shfl(r1, c) * w;
    o2 += __shfl(r2, c) * w;
  }

  float* outp = p3_new + (size_t)atom * (3 * C_DIM);
  outp[lane] = o0;
  outp[C_DIM + lane] = o1;
  outp[2 * C_DIM + lane] = o2;
  dotted[(size_t)atom * C_DIM + lane] = o0 * o0 + o1 * o1 + o2 * o2;
}

extern "C" void kernel_launch(void* const* d_in, const int* in_sizes, int n_in,
                              void* d_out, int out_size, void* d_ws, size_t ws_size,
                              hipStream_t stream) {
  const int* ind = (const int*)d_in[0];
  const float* p3 = (const float*)d_in[1];
  const float* i1 = (const float*)d_in[2];
  const float* d3 = (const float*)d_in[3];
  const float* W = (const float*)d_in[4];

  int n_pairs = in_sizes[0] / 2;
  int n_atoms = in_sizes[1] / (3 * C_DIM);

  float* agg = (float*)d_ws;  // n_atoms * 3 * 64 floats = 38.4 MB
  size_t agg_bytes = (size_t)n_atoms * 3 * C_DIM * sizeof(float);

  float* p3_new = (float*)d_out;
  float* dotted = p3_new + (size_t)n_atoms * 3 * C_DIM;

  hipMemsetAsync(agg, 0, agg_bytes, stream);

  int sblocks = (n_pairs + 3) / 4;
  scatter_kernel<<<sblocks, 256, 0, stream>>>(ind, p3, i1, d3, agg, n_pairs);

  int gblocks = (n_atoms + 3) / 4;
  gemm_kernel<<<gblocks, 256, 0, stream>>>(agg, W, p3_new, dotted, n_atoms);
}

// Round 2
// 647.150 us; speedup vs baseline: 1.4224x; 1.4224x over previous
//
#include <hip/hip_runtime.h>
#include <hip/hip_bf16.h>

#define C_DIM 64

// ---------------------------------------------------------------------------
// Pass 1: histogram of destination atoms. 800k int atomics (cheap).
__global__ __launch_bounds__(256) void hist_kernel(
    const int* __restrict__ ind, int* __restrict__ counts, int n_pairs) {
  int p = blockIdx.x * 256 + threadIdx.x;
  if (p < n_pairs) atomicAdd(&counts[ind[2 * p]], 1);
}

// ---------------------------------------------------------------------------
// Pass 2: exclusive prefix sum of counts -> cursor (single block).
__global__ __launch_bounds__(1024) void scan_kernel(
    const int* __restrict__ counts, int* __restrict__ cursor, int n) {
  __shared__ int partial[1024];
  __shared__ int partial_inc[1024];
  int t = threadIdx.x;
  int chunk = (n + 1023) / 1024;
  int b = t * chunk;
  int e = min(b + chunk, n);
  int s = 0;
  for (int k = b; k < e; ++k) s += counts[k];
  partial[t] = s;
  __syncthreads();
  if (t == 0) {
    int acc = 0;
    for (int k = 0; k < 1024; ++k) { acc += partial[k]; partial_inc[k] = acc; }
  }
  __syncthreads();
  int run = (t == 0) ? 0 : partial_inc[t - 1];
  for (int k = b; k < e; ++k) { cursor[k] = run; run += counts[k]; }
}

// ---------------------------------------------------------------------------
// Pass 3: fill buckets. cursor[a] advances from start[a] to end[a].
__global__ __launch_bounds__(256) void fill_kernel(
    const int* __restrict__ ind, int* __restrict__ cursor,
    int* __restrict__ bucket, int n_pairs) {
  int p = blockIdx.x * 256 + threadIdx.x;
  if (p < n_pairs) {
    int slot = atomicAdd(&cursor[ind[2 * p]], 1);
    bucket[slot] = p;
  }
}

// ---------------------------------------------------------------------------
// Pass 4: one wave per atom. Gather+reduce its pair list in registers,
// then fused 64x64 GEMM + self-dot via per-wave LDS round trip.
// After fill_kernel, cursor[a] == end offset; beg = end - counts[a].
__global__ __launch_bounds__(256) void reduce_gemm_kernel(
    const int* __restrict__ cursor, const int* __restrict__ counts,
    const int* __restrict__ bucket, const int* __restrict__ ind,
    const float* __restrict__ p3, const float* __restrict__ i1,
    const float* __restrict__ d3, const float* __restrict__ W,
    float* __restrict__ p3_new, float* __restrict__ dotted, int n_atoms) {
  __shared__ float Wt[C_DIM * C_DIM];          // Wt[c*64+d] = W[d*64+c]
  __shared__ __align__(16) float Abuf[4][3 * C_DIM];

  for (int idx = threadIdx.x; idx < C_DIM * C_DIM; idx += 256) {
    int d = idx >> 6, c = idx & 63;
    Wt[c * C_DIM + d] = W[idx];
  }

  int wave = threadIdx.x >> 6;
  int lane = threadIdx.x & 63;
  int atom = blockIdx.x * 4 + wave;
  bool active = atom < n_atoms;

  float r0 = 0.f, r1 = 0.f, r2 = 0.f;
  if (active) {
    int end = cursor[atom];
    int beg = end - counts[atom];
    int k = beg;
    // 2-way unrolled gather for ILP on the bucket->ind->p3 chain
    for (; k + 1 < end; k += 2) {
      int pa = bucket[k], pb = bucket[k + 1];
      int ja = ind[2 * pa + 1], jb = ind[2 * pb + 1];
      const float* pja = p3 + (size_t)ja * (3 * C_DIM);
      const float* pjb = p3 + (size_t)jb * (3 * C_DIM);
      float ga = i1[(size_t)pa * C_DIM + lane];
      float gb = i1[(size_t)pb * C_DIM + lane];
      float a0 = d3[3 * pa], a1 = d3[3 * pa + 1], a2 = d3[3 * pa + 2];
      float b0 = d3[3 * pb], b1 = d3[3 * pb + 1], b2 = d3[3 * pb + 2];
      r0 += (pja[lane] + a0) * ga + (pjb[lane] + b0) * gb;
      r1 += (pja[C_DIM + lane] + a1) * ga + (pjb[C_DIM + lane] + b1) * gb;
      r2 += (pja[2 * C_DIM + lane] + a2) * ga + (pjb[2 * C_DIM + lane] + b2) * gb;
    }
    if (k < end) {
      int p = bucket[k];
      int j = ind[2 * p + 1];
      const float* pj = p3 + (size_t)j * (3 * C_DIM);
      float g = i1[(size_t)p * C_DIM + lane];
      float a0 = d3[3 * p], a1 = d3[3 * p + 1], a2 = d3[3 * p + 2];
      r0 += (pj[lane] + a0) * g;
      r1 += (pj[C_DIM + lane] + a1) * g;
      r2 += (pj[2 * C_DIM + lane] + a2) * g;
    }
    float* A = Abuf[wave];
    A[lane] = r0;
    A[C_DIM + lane] = r1;
    A[2 * C_DIM + lane] = r2;
  }
  __syncthreads();  // covers Wt staging + per-wave A visibility

  if (active) {
    const float* A = Abuf[wave];
    float o0 = 0.f, o1 = 0.f, o2 = 0.f;
#pragma unroll
    for (int c = 0; c < C_DIM; c += 4) {
      float4 a0 = *(const float4*)&A[c];               // uniform -> broadcast
      float4 a1 = *(const float4*)&A[C_DIM + c];
      float4 a2 = *(const float4*)&A[2 * C_DIM + c];
      float w0 = Wt[(c + 0) * C_DIM + lane];           // conflict-free
      float w1 = Wt[(c + 1) * C_DIM + lane];
      float w2 = Wt[(c + 2) * C_DIM + lane];
      float w3 = Wt[(c + 3) * C_DIM + lane];
      o0 += a0.x * w0 + a0.y * w1 + a0.z * w2 + a0.w * w3;
      o1 += a1.x * w0 + a1.y * w1 + a1.z * w2 + a1.w * w3;
      o2 += a2.x * w0 + a2.y * w1 + a2.z * w2 + a2.w * w3;
    }
    float* outp = p3_new + (size_t)atom * (3 * C_DIM);
    outp[lane] = o0;
    outp[C_DIM + lane] = o1;
    outp[2 * C_DIM + lane] = o2;
    dotted[(size_t)atom * C_DIM + lane] = o0 * o0 + o1 * o1 + o2 * o2;
  }
}

extern "C" void kernel_launch(void* const* d_in, const int* in_sizes, int n_in,
                              void* d_out, int out_size, void* d_ws, size_t ws_size,
                              hipStream_t stream) {
  const int* ind = (const int*)d_in[0];
  const float* p3 = (const float*)d_in[1];
  const float* i1 = (const float*)d_in[2];
  const float* d3 = (const float*)d_in[3];
  const float* W = (const float*)d_in[4];

  int n_pairs = in_sizes[0] / 2;
  int n_atoms = in_sizes[1] / (3 * C_DIM);

  int* counts = (int*)d_ws;             // n_atoms ints
  int* cursor = counts + n_atoms;       // n_atoms ints
  int* bucket = cursor + n_atoms;       // n_pairs ints

  float* p3_new = (float*)d_out;
  float* dotted = p3_new + (size_t)n_atoms * 3 * C_DIM;

  hipMemsetAsync(counts, 0, (size_t)n_atoms * sizeof(int), stream);

  int pblocks = (n_pairs + 255) / 256;
  hist_kernel<<<pblocks, 256, 0, stream>>>(ind, counts, n_pairs);
  scan_kernel<<<1, 1024, 0, stream>>>(counts, cursor, n_atoms);
  fill_kernel<<<pblocks, 256, 0, stream>>>(ind, cursor, bucket, n_pairs);

  int ablocks = (n_atoms + 3) / 4;
  reduce_gemm_kernel<<<ablocks, 256, 0, stream>>>(
      cursor, counts, bucket, ind, p3, i1, d3, W, p3_new, dotted, n_atoms);
}

// Round 3
// 589.307 us; speedup vs baseline: 1.5620x; 1.0982x over previous
//
#include <hip/hip_runtime.h>
#include <hip/hip_bf16.h>

#define C_DIM 64
#define WT_STRIDE 65  // +1 pad: staging writes (stride-65 words) hit distinct banks

// ---------------------------------------------------------------------------
// Pass 1: histogram of destination atoms.
__global__ __launch_bounds__(256) void hist_kernel(
    const int* __restrict__ ind, int* __restrict__ counts, int n_pairs) {
  int p = blockIdx.x * 256 + threadIdx.x;
  if (p < n_pairs) atomicAdd(&counts[((const int2*)ind)[p].x], 1);
}

// ---------------------------------------------------------------------------
// Pass 2: exclusive prefix sum, single block, shfl-based two-level scan.
__global__ __launch_bounds__(1024) void scan_kernel(
    const int* __restrict__ counts, int* __restrict__ cursor, int n) {
  __shared__ int wsum[16];
  int t = threadIdx.x;
  int lane = t & 63, wave = t >> 6;
  int chunk = (n + 1023) / 1024;
  int b = t * chunk;
  int e = min(b + chunk, n);
  int s = 0;
  for (int k = b; k < e; ++k) s += counts[k];
  // inclusive shfl scan of per-thread sums within the wave
  int inc = s;
#pragma unroll
  for (int d = 1; d < 64; d <<= 1) {
    int v = __shfl_up(inc, d);
    if (lane >= d) inc += v;
  }
  if (lane == 63) wsum[wave] = inc;
  __syncthreads();
  if (wave == 0 && lane < 16) {
    int v = wsum[lane];
    int iv = v;
#pragma unroll
    for (int d = 1; d < 16; d <<= 1) {
      int u = __shfl_up(iv, d);
      if (lane >= d) iv += u;
    }
    wsum[lane] = iv - v;  // exclusive wave offset
  }
  __syncthreads();
  int run = wsum[wave] + (inc - s);  // global exclusive prefix for this thread
  for (int k = b; k < e; ++k) { cursor[k] = run; run += counts[k]; }
}

// ---------------------------------------------------------------------------
// Pass 3: fill buckets with (p, j) so the hot loop skips the ind[] hop.
__global__ __launch_bounds__(256) void fill_kernel(
    const int* __restrict__ ind, int* __restrict__ cursor,
    int2* __restrict__ bucket, int n_pairs) {
  int p = blockIdx.x * 256 + threadIdx.x;
  if (p < n_pairs) {
    int2 ij = ((const int2*)ind)[p];
    int slot = atomicAdd(&cursor[ij.x], 1);
    bucket[slot] = make_int2(p, ij.y);
  }
}

// ---------------------------------------------------------------------------
// Pass 4: one wave per atom; register reduce + fused 64x64 GEMM + self-dot.
__global__ __launch_bounds__(256) void reduce_gemm_kernel(
    const int* __restrict__ cursor, const int* __restrict__ counts,
    const int2* __restrict__ bucket,
    const float* __restrict__ p3, const float* __restrict__ i1,
    const float* __restrict__ d3, const float* __restrict__ W,
    float* __restrict__ p3_new, float* __restrict__ dotted, int n_atoms) {
  __shared__ float Wt[C_DIM * WT_STRIDE];       // Wt[c*65+d] = W[d*64+c]
  __shared__ __align__(16) float Abuf[4][3 * C_DIM];

  for (int idx = threadIdx.x; idx < C_DIM * C_DIM; idx += 256) {
    int d = idx >> 6, c = idx & 63;
    Wt[c * WT_STRIDE + d] = W[idx];             // padded: conflict-free store
  }

  int wave = threadIdx.x >> 6;
  int lane = threadIdx.x & 63;
  int atom = blockIdx.x * 4 + wave;
  bool active = atom < n_atoms;

  float r0 = 0.f, r1 = 0.f, r2 = 0.f;
  if (active) {
    int end = cursor[atom];
    int beg = end - counts[atom];
    int k = beg;
    // 4-way unrolled: 4 independent bucket->{p3,i1,d3} chains in flight
    for (; k + 3 < end; k += 4) {
      int2 ij0 = bucket[k], ij1 = bucket[k + 1], ij2 = bucket[k + 2], ij3 = bucket[k + 3];
      const float* q0 = p3 + (size_t)ij0.y * (3 * C_DIM);
      const float* q1 = p3 + (size_t)ij1.y * (3 * C_DIM);
      const float* q2 = p3 + (size_t)ij2.y * (3 * C_DIM);
      const float* q3 = p3 + (size_t)ij3.y * (3 * C_DIM);
      float g0 = i1[(size_t)ij0.x * C_DIM + lane];
      float g1 = i1[(size_t)ij1.x * C_DIM + lane];
      float g2 = i1[(size_t)ij2.x * C_DIM + lane];
      float g3 = i1[(size_t)ij3.x * C_DIM + lane];
      float e00 = d3[3 * ij0.x], e01 = d3[3 * ij0.x + 1], e02 = d3[3 * ij0.x + 2];
      float e10 = d3[3 * ij1.x], e11 = d3[3 * ij1.x + 1], e12 = d3[3 * ij1.x + 2];
      float e20 = d3[3 * ij2.x], e21 = d3[3 * ij2.x + 1], e22 = d3[3 * ij2.x + 2];
      float e30 = d3[3 * ij3.x], e31 = d3[3 * ij3.x + 1], e32 = d3[3 * ij3.x + 2];
      r0 += (q0[lane] + e00) * g0 + (q1[lane] + e10) * g1 +
            (q2[lane] + e20) * g2 + (q3[lane] + e30) * g3;
      r1 += (q0[C_DIM + lane] + e01) * g0 + (q1[C_DIM + lane] + e11) * g1 +
            (q2[C_DIM + lane] + e21) * g2 + (q3[C_DIM + lane] + e31) * g3;
      r2 += (q0[2 * C_DIM + lane] + e02) * g0 + (q1[2 * C_DIM + lane] + e12) * g1 +
            (q2[2 * C_DIM + lane] + e22) * g2 + (q3[2 * C_DIM + lane] + e32) * g3;
    }
    for (; k < end; ++k) {
      int2 ij = bucket[k];
      const float* q = p3 + (size_t)ij.y * (3 * C_DIM);
      float g = i1[(size_t)ij.x * C_DIM + lane];
      float e0 = d3[3 * ij.x], e1 = d3[3 * ij.x + 1], e2 = d3[3 * ij.x + 2];
      r0 += (q[lane] + e0) * g;
      r1 += (q[C_DIM + lane] + e1) * g;
      r2 += (q[2 * C_DIM + lane] + e2) * g;
    }
    float* A = Abuf[wave];
    A[lane] = r0;
    A[C_DIM + lane] = r1;
    A[2 * C_DIM + lane] = r2;
  }
  __syncthreads();  // covers Wt staging + per-wave A visibility

  if (active) {
    const float* A = Abuf[wave];
    float o0 = 0.f, o1 = 0.f, o2 = 0.f;
#pragma unroll
    for (int c = 0; c < C_DIM; c += 4) {
      float4 a0 = *(const float4*)&A[c];              // wave-uniform -> broadcast
      float4 a1 = *(const float4*)&A[C_DIM + c];
      float4 a2 = *(const float4*)&A[2 * C_DIM + c];
      float w0 = Wt[(c + 0) * WT_STRIDE + lane];      // consecutive -> conflict-free
      float w1 = Wt[(c + 1) * WT_STRIDE + lane];
      float w2 = Wt[(c + 2) * WT_STRIDE + lane];
      float w3 = Wt[(c + 3) * WT_STRIDE + lane];
      o0 += a0.x * w0 + a0.y * w1 + a0.z * w2 + a0.w * w3;
      o1 += a1.x * w0 + a1.y * w1 + a1.z * w2 + a1.w * w3;
      o2 += a2.x * w0 + a2.y * w1 + a2.z * w2 + a2.w * w3;
    }
    float* outp = p3_new + (size_t)atom * (3 * C_DIM);
    outp[lane] = o0;
    outp[C_DIM + lane] = o1;
    outp[2 * C_DIM + lane] = o2;
    dotted[(size_t)atom * C_DIM + lane] = o0 * o0 + o1 * o1 + o2 * o2;
  }
}

extern "C" void kernel_launch(void* const* d_in, const int* in_sizes, int n_in,
                              void* d_out, int out_size, void* d_ws, size_t ws_size,
                              hipStream_t stream) {
  const int* ind = (const int*)d_in[0];
  const float* p3 = (const float*)d_in[1];
  const float* i1 = (const float*)d_in[2];
  const float* d3 = (const float*)d_in[3];
  const float* W = (const float*)d_in[4];

  int n_pairs = in_sizes[0] / 2;
  int n_atoms = in_sizes[1] / (3 * C_DIM);

  int* counts = (int*)d_ws;                       // n_atoms ints
  int* cursor = counts + n_atoms;                 // n_atoms ints
  int2* bucket = (int2*)(cursor + n_atoms);       // n_pairs int2 (8B-aligned: 2*n_atoms ints precede when n_atoms even)

  float* p3_new = (float*)d_out;
  float* dotted = p3_new + (size_t)n_atoms * 3 * C_DIM;

  hipMemsetAsync(counts, 0, (size_t)n_atoms * sizeof(int), stream);

  int pblocks = (n_pairs + 255) / 256;
  hist_kernel<<<pblocks, 256, 0, stream>>>(ind, counts, n_pairs);
  scan_kernel<<<1, 1024, 0, stream>>>(counts, cursor, n_atoms);
  fill_kernel<<<pblocks, 256, 0, stream>>>(ind, cursor, bucket, n_pairs);

  int ablocks = (n_atoms + 3) / 4;
  reduce_gemm_kernel<<<ablocks, 256, 0, stream>>>(
      cursor, counts, bucket, p3, i1, d3, W, p3_new, dotted, n_atoms);
}

// Round 4
// 542.970 us; speedup vs baseline: 1.6953x; 1.0853x over previous
//
#include <hip/hip_runtime.h>
#include <hip/hip_bf16.h>

#define C_DIM 64
#define WT_STRIDE 65

// ---------------------------------------------------------------------------
// Pass 1: histogram of destination atoms.
__global__ __launch_bounds__(256) void hist_kernel(
    const int* __restrict__ ind, int* __restrict__ counts, int n_pairs) {
  int p = blockIdx.x * 256 + threadIdx.x;
  if (p < n_pairs) atomicAdd(&counts[((const int2*)ind)[p].x], 1);
}

// ---------------------------------------------------------------------------
// Pass 2a: per-block (256-elem tile) sums.
__global__ __launch_bounds__(256) void scan_part_kernel(
    const int* __restrict__ counts, int* __restrict__ bsum, int n) {
  int i = blockIdx.x * 256 + threadIdx.x;
  int v = (i < n) ? counts[i] : 0;
#pragma unroll
  for (int d = 32; d > 0; d >>= 1) v += __shfl_down(v, d);
  __shared__ int ws[4];
  int lane = threadIdx.x & 63, wave = threadIdx.x >> 6;
  if (lane == 0) ws[wave] = v;
  __syncthreads();
  if (threadIdx.x == 0) bsum[blockIdx.x] = ws[0] + ws[1] + ws[2] + ws[3];
}

// ---------------------------------------------------------------------------
// Pass 2b: exclusive scan of block sums (single block, up to 1024 elems).
__global__ __launch_bounds__(1024) void scan_mid_kernel(
    const int* __restrict__ bsum, int* __restrict__ boff, int n) {
  __shared__ int wsum[16];
  int t = threadIdx.x;
  int lane = t & 63, wave = t >> 6;
  int s = (t < n) ? bsum[t] : 0;
  int inc = s;
#pragma unroll
  for (int d = 1; d < 64; d <<= 1) {
    int v = __shfl_up(inc, d);
    if (lane >= d) inc += v;
  }
  if (lane == 63) wsum[wave] = inc;
  __syncthreads();
  if (wave == 0 && lane < 16) {
    int v = wsum[lane];
    int iv = v;
#pragma unroll
    for (int d = 1; d < 16; d <<= 1) {
      int u = __shfl_up(iv, d);
      if (lane >= d) iv += u;
    }
    wsum[lane] = iv - v;
  }
  __syncthreads();
  if (t < n) boff[t] = wsum[wave] + (inc - s);
}

// ---------------------------------------------------------------------------
// Pass 2c: finalize cursor = global exclusive scan of counts.
__global__ __launch_bounds__(256) void scan_fin_kernel(
    const int* __restrict__ counts, const int* __restrict__ boff,
    int* __restrict__ cursor, int n) {
  int i = blockIdx.x * 256 + threadIdx.x;
  int v = (i < n) ? counts[i] : 0;
  int lane = threadIdx.x & 63, wave = threadIdx.x >> 6;
  int inc = v;
#pragma unroll
  for (int d = 1; d < 64; d <<= 1) {
    int u = __shfl_up(inc, d);
    if (lane >= d) inc += u;
  }
  __shared__ int ws[4];
  if (lane == 63) ws[wave] = inc;
  __syncthreads();
  int woff = 0;
  if (wave > 0) woff = ws[0];
  if (wave > 1) woff += ws[1];
  if (wave > 2) woff += ws[2];
  if (i < n) cursor[i] = boff[blockIdx.x] + woff + (inc - v);
}

// ---------------------------------------------------------------------------
// Pass 3: fill buckets. bkt_pj = {p, j}; bkt_d = {d3x, d3y, d3z, -}.
__global__ __launch_bounds__(256) void fill_kernel(
    const int* __restrict__ ind, const float* __restrict__ d3,
    int* __restrict__ cursor, int2* __restrict__ bkt_pj,
    float4* __restrict__ bkt_d, int n_pairs) {
  int p = blockIdx.x * 256 + threadIdx.x;
  if (p < n_pairs) {
    int2 ij = ((const int2*)ind)[p];
    int slot = atomicAdd(&cursor[ij.x], 1);
    bkt_pj[slot] = make_int2(p, ij.y);
    bkt_d[slot] = make_float4(d3[3 * p], d3[3 * p + 1], d3[3 * p + 2], 0.f);
  }
}

// ---------------------------------------------------------------------------
// Pass 4: one wave per atom. 16-lane-group vectorized gather:
// lane = 16*g + sl; group g handles pair (base+g); lane holds channels
// 4*sl..4*sl+3 as float4. One float4 instr moves a full 256B row per group.
__global__ __launch_bounds__(256) void reduce_gemm_kernel(
    const int* __restrict__ cursor, const int* __restrict__ counts,
    const int2* __restrict__ bkt_pj, const float4* __restrict__ bkt_d,
    const float* __restrict__ p3, const float* __restrict__ i1,
    const float* __restrict__ W,
    float* __restrict__ p3_new, float* __restrict__ dotted, int n_atoms) {
  __shared__ float Wt[C_DIM * WT_STRIDE];       // Wt[c*65+d] = W[d*64+c]
  __shared__ __align__(16) float Abuf[4][3 * C_DIM];

  for (int idx = threadIdx.x; idx < C_DIM * C_DIM; idx += 256) {
    int d = idx >> 6, c = idx & 63;
    Wt[c * WT_STRIDE + d] = W[idx];
  }

  int wave = threadIdx.x >> 6;
  int lane = threadIdx.x & 63;
  int atom = blockIdx.x * 4 + wave;
  bool active = atom < n_atoms;

  int g = lane >> 4;        // pair subgroup 0..3
  int sl = lane & 15;       // sublane -> channels 4*sl..4*sl+3

  float4 r0 = make_float4(0.f, 0.f, 0.f, 0.f);
  float4 r1 = r0, r2 = r0;

  if (active) {
    int end = cursor[atom];
    int beg = end - counts[atom];
    for (int base = beg; base < end; base += 4) {
      int k = base + g;
      if (k < end) {
        int2 pj = bkt_pj[k];
        float4 dv = bkt_d[k];
        const float4* gt4 = (const float4*)(i1 + (size_t)pj.x * C_DIM);
        const float4* q4 = (const float4*)(p3 + (size_t)pj.y * (3 * C_DIM));
        float4 gt = gt4[sl];
        float4 q0 = q4[sl];
        float4 q1 = q4[16 + sl];
        float4 q2 = q4[32 + sl];
        r0.x += (q0.x + dv.x) * gt.x; r0.y += (q0.y + dv.x) * gt.y;
        r0.z += (q0.z + dv.x) * gt.z; r0.w += (q0.w + dv.x) * gt.w;
        r1.x += (q1.x + dv.y) * gt.x; r1.y += (q1.y + dv.y) * gt.y;
        r1.z += (q1.z + dv.y) * gt.z; r1.w += (q1.w + dv.y) * gt.w;
        r2.x += (q2.x + dv.z) * gt.x; r2.y += (q2.y + dv.z) * gt.y;
        r2.z += (q2.z + dv.z) * gt.z; r2.w += (q2.w + dv.z) * gt.w;
      }
    }
    // combine the 4 pair-subgroups: lanes L, L^16, L^32, L^48 hold same channels
#pragma unroll
    for (int m = 16; m < 64; m <<= 1) {
      r0.x += __shfl_xor(r0.x, m); r0.y += __shfl_xor(r0.y, m);
      r0.z += __shfl_xor(r0.z, m); r0.w += __shfl_xor(r0.w, m);
      r1.x += __shfl_xor(r1.x, m); r1.y += __shfl_xor(r1.y, m);
      r1.z += __shfl_xor(r1.z, m); r1.w += __shfl_xor(r1.w, m);
      r2.x += __shfl_xor(r2.x, m); r2.y += __shfl_xor(r2.y, m);
      r2.z += __shfl_xor(r2.z, m); r2.w += __shfl_xor(r2.w, m);
    }
    if (g == 0) {
      float4* A = (float4*)Abuf[wave];
      A[sl] = r0;
      A[16 + sl] = r1;
      A[32 + sl] = r2;
    }
  }
  __syncthreads();  // covers Wt staging + per-wave A visibility

  if (active) {
    const float* A = Abuf[wave];
    float o0 = 0.f, o1 = 0.f, o2 = 0.f;
#pragma unroll
    for (int c = 0; c < C_DIM; c += 4) {
      float4 a0 = *(const float4*)&A[c];              // wave-uniform -> broadcast
      float4 a1 = *(const float4*)&A[C_DIM + c];
      float4 a2 = *(const float4*)&A[2 * C_DIM + c];
      float w0 = Wt[(c + 0) * WT_STRIDE + lane];      // conflict-free
      float w1 = Wt[(c + 1) * WT_STRIDE + lane];
      float w2 = Wt[(c + 2) * WT_STRIDE + lane];
      float w3 = Wt[(c + 3) * WT_STRIDE + lane];
      o0 += a0.x * w0 + a0.y * w1 + a0.z * w2 + a0.w * w3;
      o1 += a1.x * w0 + a1.y * w1 + a1.z * w2 + a1.w * w3;
      o2 += a2.x * w0 + a2.y * w1 + a2.z * w2 + a2.w * w3;
    }
    float* outp = p3_new + (size_t)atom * (3 * C_DIM);
    outp[lane] = o0;
    outp[C_DIM + lane] = o1;
    outp[2 * C_DIM + lane] = o2;
    dotted[(size_t)atom * C_DIM + lane] = o0 * o0 + o1 * o1 + o2 * o2;
  }
}

extern "C" void kernel_launch(void* const* d_in, const int* in_sizes, int n_in,
                              void* d_out, int out_size, void* d_ws, size_t ws_size,
                              hipStream_t stream) {
  const int* ind = (const int*)d_in[0];
  const float* p3 = (const float*)d_in[1];
  const float* i1 = (const float*)d_in[2];
  const float* d3 = (const float*)d_in[3];
  const float* W = (const float*)d_in[4];

  int n_pairs = in_sizes[0] / 2;
  int n_atoms = in_sizes[1] / (3 * C_DIM);

  int nb = (n_atoms + 255) / 256;                 // scan tiles (196)

  int* counts = (int*)d_ws;                       // n_atoms
  int* cursor = counts + n_atoms;                 // n_atoms
  int* bsum = cursor + n_atoms;                   // nb
  int* boff = bsum + nb;                          // nb
  // align bkt_d to 16B
  size_t off = (size_t)(2 * n_atoms + 2 * nb);
  off = (off + 3) & ~(size_t)3;
  float4* bkt_d = (float4*)((int*)d_ws + off);    // n_pairs float4 (12.8 MB)
  int2* bkt_pj = (int2*)(bkt_d + n_pairs);        // n_pairs int2 (6.4 MB)

  float* p3_new = (float*)d_out;
  float* dotted = p3_new + (size_t)n_atoms * 3 * C_DIM;

  hipMemsetAsync(counts, 0, (size_t)n_atoms * sizeof(int), stream);

  int pblocks = (n_pairs + 255) / 256;
  hist_kernel<<<pblocks, 256, 0, stream>>>(ind, counts, n_pairs);
  scan_part_kernel<<<nb, 256, 0, stream>>>(counts, bsum, n_atoms);
  scan_mid_kernel<<<1, 1024, 0, stream>>>(bsum, boff, nb);
  scan_fin_kernel<<<nb, 256, 0, stream>>>(counts, boff, cursor, n_atoms);
  fill_kernel<<<pblocks, 256, 0, stream>>>(ind, d3, cursor, bkt_pj, bkt_d, n_pairs);

  int ablocks = (n_atoms + 3) / 4;
  reduce_gemm_kernel<<<ablocks, 256, 0, stream>>>(
      cursor, counts, bkt_pj, bkt_d, p3, i1, W, p3_new, dotted, n_atoms);
}